// Round 10
// baseline (1417.428 us; speedup 1.0000x reference)
//
#include <hip/hip_runtime.h>
#include <cstdint>
#include <cstddef>

#define NV    32768
#define EMB   512
#define DEG   32
#define NC    50
#define H3DIM 281
#define GROWS 32767            // N-1 gumbel rows
#define WGUARD (1u << 20)      // bounded spin: no infinite hang

// ---------------- threefry2x32, key = jax.random.key(42) -> (0, 42) ----------------
__device__ __forceinline__ void threefry(unsigned x0, unsigned x1,
                                         unsigned& y0, unsigned& y1) {
  const unsigned ks0 = 0u, ks1 = 42u, ks2 = 0x1BD11BDAu ^ 42u;
  x0 += ks0; x1 += ks1;
#define TFR(r) { x0 += x1; x1 = (x1 << (r)) | (x1 >> (32 - (r))); x1 ^= x0; }
  TFR(13) TFR(15) TFR(26) TFR(6)  x0 += ks1; x1 += ks2 + 1u;
  TFR(17) TFR(29) TFR(16) TFR(24) x0 += ks2; x1 += ks0 + 2u;
  TFR(13) TFR(15) TFR(26) TFR(6)  x0 += ks0; x1 += ks1 + 3u;
  TFR(17) TFR(29) TFR(16) TFR(24) x0 += ks1; x1 += ks2 + 4u;
  TFR(13) TFR(15) TFR(26) TFR(6)  x0 += ks2; x1 += ks0 + 5u;
#undef TFR
  y0 = x0; y1 = x1;
}

// partitionable threefry (jax >= 0.5 default): bits(i) = xor of threefry(key, (0, i))
__device__ __forceinline__ float gumbel_at(unsigned idx) {
  unsigned y0, y1;
  threefry(0u, idx, y0, y1);
  unsigned bits = y0 ^ y1;
  unsigned fb = (bits >> 9) | 0x3F800000u;
  float f = __uint_as_float(fb) - 1.0f;
  float u = fmaxf(f, 1.17549435e-38f);
  return -logf(-logf(u));
}

// ---------------- 128x128 fp32 GEMM, BK=32 (M%128==0, K%32==0) ----------------
// Per-output arithmetic: single accumulator, k-ascending fmaf — bit-identical
// across all scheduling variants (rounds 2-9 all absmax 0.0).
// B-tile staged via global_load_lds (direct global->LDS DMA, width 16) when
// nguard==0 (N multiple of f4 coverage); guarded VGPR path otherwise (L3, N=281).
__global__ __launch_bounds__(256) void gemm128(
    const float* __restrict__ A, const float* __restrict__ W,
    const float* __restrict__ bias, float* __restrict__ C,
    int M, int N, int K, int act, int nguard) {
  __shared__ float As[32][132];   // [k][m], padded
  __shared__ float Bs[32][128];   // [k][n]
  int tid = threadIdx.x;
  int bm = blockIdx.y * 128;
  int bn = blockIdx.x * 128;
  int tx = tid & 15, ty = tid >> 4;  // 16x16 threads, 8x8 micro-tile
  int wave = tid >> 6, lane = tid & 63;
  float acc[8][8];
#pragma unroll
  for (int i = 0; i < 8; ++i)
#pragma unroll
    for (int j = 0; j < 8; ++j) acc[i][j] = 0.f;

  for (int k0 = 0; k0 < K; k0 += 32) {
    // A tile: 128 rows x 32 k = 1024 float4, 4 per thread (transposed store)
#pragma unroll
    for (int l = 0; l < 4; ++l) {
      int idx = tid + l * 256;
      int row = idx >> 3, cc = (idx & 7) * 4;
      float4 av = *(const float4*)(A + (size_t)(bm + row) * K + (k0 + cc));
      As[cc + 0][row] = av.x; As[cc + 1][row] = av.y;
      As[cc + 2][row] = av.z; As[cc + 3][row] = av.w;
    }
    // B tile: 32 k-rows x 128 cols = 1024 float4
    if (!nguard) {
      // direct global->LDS DMA: dest = wave-uniform base + lane*16 (exactly our map)
#pragma unroll
      for (int l = 0; l < 4; ++l) {
        int idx = l * 256 + wave * 64 + lane;
        int row = idx >> 5, cc = (idx & 31) * 4;
        const float* gp = W + (size_t)(k0 + row) * N + (bn + cc);
        char* lp = (char*)Bs + (size_t)(l * 256 + wave * 64) * 16;
        __builtin_amdgcn_global_load_lds(
            (const __attribute__((address_space(1))) void*)gp,
            (__attribute__((address_space(3))) void*)lp, 16, 0, 0);
      }
    } else {
#pragma unroll
      for (int l = 0; l < 4; ++l) {
        int idx = tid + l * 256;
        int row = idx >> 5, cc = (idx & 31) * 4;
        int gc = bn + cc;
        const float* bp = W + (size_t)(k0 + row) * N + gc;
        float4 bv;
        bv.x = (gc + 0 < N) ? bp[0] : 0.f;
        bv.y = (gc + 1 < N) ? bp[1] : 0.f;
        bv.z = (gc + 2 < N) ? bp[2] : 0.f;
        bv.w = (gc + 3 < N) ? bp[3] : 0.f;
        *(float4*)&Bs[row][cc] = bv;
      }
    }
    __syncthreads();
#pragma unroll
    for (int kk = 0; kk < 32; ++kk) {
      float4 a0 = *(const float4*)&As[kk][ty * 8];
      float4 a1 = *(const float4*)&As[kk][ty * 8 + 4];
      float4 b0 = *(const float4*)&Bs[kk][tx * 8];
      float4 b1 = *(const float4*)&Bs[kk][tx * 8 + 4];
      float a[8] = {a0.x, a0.y, a0.z, a0.w, a1.x, a1.y, a1.z, a1.w};
      float b[8] = {b0.x, b0.y, b0.z, b0.w, b1.x, b1.y, b1.z, b1.w};
#pragma unroll
      for (int i = 0; i < 8; ++i)
#pragma unroll
        for (int j = 0; j < 8; ++j)
          acc[i][j] = fmaf(a[i], b[j], acc[i][j]);
    }
    __syncthreads();
  }
#pragma unroll
  for (int i = 0; i < 8; ++i) {
    int row = bm + ty * 8 + i;
#pragma unroll
    for (int j = 0; j < 8; ++j) {
      int cn = bn + tx * 8 + j;
      if (cn < N) {
        float v = acc[i][j] + bias[cn];
        if (act) v = (v >= 0.f) ? v : 0.01f * v;
        C[(size_t)row * N + cn] = v;
      }
    }
  }
}

// ---------------- L4 GEMM (K=281, N=50) with fused y = logit + gumbel epilogue ----------------
#define TILE 64
#define BK   16
__global__ __launch_bounds__(256) void gemm_l4(
    const float* __restrict__ A, const float* __restrict__ W,
    const float* __restrict__ bias, float* __restrict__ Clog,
    float* __restrict__ y, const int* __restrict__ pos,
    int row0, int N, int K) {
  __shared__ float As[BK][TILE + 1];
  __shared__ float Bs[BK][TILE];
  int tid = threadIdx.x;
  int bm = blockIdx.y * TILE;
  int tx = tid & 15, ty = tid >> 4;
  int ar = tid >> 2;
  int ac = (tid & 3) * 4;
  int br = tid >> 4;
  int bc = (tid & 15) * 4;
  float acc[4][4] = {{0.f,0.f,0.f,0.f},{0.f,0.f,0.f,0.f},{0.f,0.f,0.f,0.f},{0.f,0.f,0.f,0.f}};

  for (int k0 = 0; k0 < K; k0 += BK) {
    {
      int gk = k0 + ac;
      const float* ap = A + (size_t)(bm + ar) * K + gk;
      As[ac + 0][ar] = (gk + 0 < K) ? ap[0] : 0.f;
      As[ac + 1][ar] = (gk + 1 < K) ? ap[1] : 0.f;
      As[ac + 2][ar] = (gk + 2 < K) ? ap[2] : 0.f;
      As[ac + 3][ar] = (gk + 3 < K) ? ap[3] : 0.f;
    }
    {
      int gr = k0 + br;
      const float* bp = W + (size_t)gr * N + bc;
      bool rok = gr < K;
      Bs[br][bc + 0] = (rok && bc + 0 < N) ? bp[0] : 0.f;
      Bs[br][bc + 1] = (rok && bc + 1 < N) ? bp[1] : 0.f;
      Bs[br][bc + 2] = (rok && bc + 2 < N) ? bp[2] : 0.f;
      Bs[br][bc + 3] = (rok && bc + 3 < N) ? bp[3] : 0.f;
    }
    __syncthreads();
#pragma unroll
    for (int kk = 0; kk < BK; ++kk) {
      float a[4], b[4];
#pragma unroll
      for (int i = 0; i < 4; ++i) a[i] = As[kk][ty * 4 + i];
#pragma unroll
      for (int j = 0; j < 4; ++j) b[j] = Bs[kk][tx * 4 + j];
#pragma unroll
      for (int i = 0; i < 4; ++i)
#pragma unroll
        for (int j = 0; j < 4; ++j)
          acc[i][j] = fmaf(a[i], b[j], acc[i][j]);
    }
    __syncthreads();
  }
#pragma unroll
  for (int i = 0; i < 4; ++i) {
    int v = row0 + bm + ty * 4 + i;   // global vertex id
    int p = pos[v];
#pragma unroll
    for (int j = 0; j < 4; ++j) {
      int cn = tx * 4 + j;
      if (cn < N) {
        float val = acc[i][j] + bias[cn];
        Clog[(size_t)v * N + cn] = val;
        if (p > 0)   // y row p; same add order as reference (logit + gumbel)
          y[(size_t)p * N + cn] = val + gumbel_at((unsigned)((p - 1) * N + cn));
      }
    }
  }
}

// ---------------- init: colors/pos/counters in one pass ----------------
__global__ void initpos_kernel(const int* __restrict__ order,
                               int* __restrict__ colors, int* __restrict__ pos,
                               unsigned long long* __restrict__ used,
                               int* __restrict__ icnt) {
  int i = blockIdx.x * 256 + threadIdx.x;
  if (i < NV) { colors[i] = -1; pos[order[i]] = i; }
  if (i == 0) { *used = 0ull; icnt[0] = 0; icnt[1] = 0; }
}

// ---------------- per-position descending-sort permutation of y (50 values) ----------------
// rank[c] = #{c' : y[c'] > y[c]  or  (y[c']==y[c] and c'<c)}  -> stable descending order.
// First unmasked color in this order == argmax of masked y (jnp.argmax tie-break).
__global__ __launch_bounds__(256) void rank_kernel(const float* __restrict__ y,
                                                   unsigned* __restrict__ perm) {
  __shared__ unsigned char sh[4][64];
  int w = threadIdx.x >> 6, lane = threadIdx.x & 63;
  int p = blockIdx.x * 4 + w + 1;
  bool active = (p < NV);
  float val = (active && lane < NC) ? y[(size_t)p * NC + lane] : 0.f;
  int rank = 0;
#pragma unroll
  for (int c = 0; c < NC; ++c) {
    float o = __shfl(val, c);
    rank += (o > val) || (o == val && c < lane);
  }
  if (active && lane < NC) sh[w][rank] = (unsigned char)lane;
  __syncthreads();
  if (active && lane < 13) perm[(size_t)p * 13 + lane] = ((unsigned*)sh[w])[lane];
}

// ---------------- true-dependency dataflow coloring, register-rank fire ----------------
// One lane per position; spins (RELAXED agent-scope, no sleep — polls are cheap
// L2/IC reads) on its earlier-neighbor colors. Fire = register rank-list scan.
__global__ __launch_bounds__(64) void color_dataflow4(
    const unsigned* __restrict__ perm, const int* __restrict__ adj,
    const int* __restrict__ order, const int* __restrict__ pos,
    int* colors, unsigned long long* used) {
  int lane = threadIdx.x;
  int p = blockIdx.x * 64 + lane;     // position owned by this lane
  int v = order[p];
  int u[DEG];
  const int* arow = adj + (size_t)v * DEG;
#pragma unroll
  for (int j = 0; j < DEG; ++j) u[j] = arow[j];
  unsigned pend = 0;
#pragma unroll
  for (int j = 0; j < DEG; ++j)
    if (pos[u[j]] < p) pend |= 1u << j;
  unsigned pm[13];
#pragma unroll
  for (int i = 0; i < 13; ++i) pm[i] = perm[(size_t)p * 13 + i];  // row 0 garbage, unused

  unsigned long long colmask = 0ull;
  unsigned long long um = 0ull;
  bool done = false;
  if (p == 0) {
    __hip_atomic_store(colors + v, 0, __ATOMIC_RELAXED, __HIP_MEMORY_SCOPE_AGENT);
    um = 1ull; done = true; pend = 0;
  }
  unsigned guard = 0;
  while (true) {
    unsigned newpend = pend;
#pragma unroll
    for (int j = 0; j < DEG; ++j) {
      if (pend & (1u << j)) {
        int c = __hip_atomic_load(colors + u[j], __ATOMIC_RELAXED, __HIP_MEMORY_SCOPE_AGENT);
        if (c >= 0) { colmask |= 1ull << c; newpend &= ~(1u << j); }
      }
    }
    pend = newpend;
    if (++guard > WGUARD) pend = 0;  // halt guarantee: fire with partial mask
    if (!done && pend == 0) {
      int bc = -1;
#pragma unroll
      for (int r = 0; r < NC; ++r) {   // constant indices -> stays in registers
        int c = (int)((pm[r >> 2] >> ((r & 3) * 8)) & 0xffu);
        if (bc < 0 && !((colmask >> c) & 1ull)) bc = c;
      }
      __hip_atomic_store(colors + v, bc, __ATOMIC_RELAXED, __HIP_MEMORY_SCOPE_AGENT);
      um |= 1ull << bc;
      done = true;
    }
    if (__ballot(pend != 0) == 0ull) break;  // every lane in wave has fired
  }
#pragma unroll
  for (int off = 1; off < 64; off <<= 1) um |= __shfl_xor(um, off);
  if (lane == 0) atomicOr(used, um);
}

// ---------------- parallel logp reconstruction (one wave per position) ----------------
__global__ __launch_bounds__(256) void logp_kernel(
    const float* __restrict__ logit, const int* __restrict__ adj,
    const int* __restrict__ order, const int* __restrict__ pos,
    const int* __restrict__ colors, float* __restrict__ term) {
  int wid = blockIdx.x * 4 + (threadIdx.x >> 6);
  int lane = threadIdx.x & 63;
  int p = wid + 1;
  if (p >= NV) return;
  int v = order[p];
  int cchosen = colors[v];
  unsigned long long bits = 0ull;
  if (lane < DEG) {
    int u = adj[v * DEG + lane];
    if (pos[u] < p) bits = 1ull << colors[u];  // color at time p == final color
  }
#pragma unroll
  for (int off = 1; off < 64; off <<= 1) bits |= __shfl_xor(bits, off);
  bool masked = (bits >> lane) & 1ull;
  float xv = (lane < NC) ? logit[v * NC + lane] : -INFINITY;
  float x = (lane < NC && !masked) ? xv : -INFINITY;
  float xm = x;
#pragma unroll
  for (int off = 1; off < 64; off <<= 1) xm = fmaxf(xm, __shfl_xor(xm, off));
  float ex = expf(x - xm);
  float S = ex;
#pragma unroll
  for (int off = 1; off < 64; off <<= 1) S += __shfl_xor(S, off);
  float ec = __shfl(ex, cchosen);
  float pr = ec / S;
  if (lane == 0) term[p - 1] = logf(pr + 1e-8f) - logf(1e-8f);
}

// ---------------- deterministic sum of 32767 terms ----------------
__global__ __launch_bounds__(256) void sum_kernel(const float* __restrict__ term,
                                                  float* __restrict__ scal) {
  __shared__ float sm[256];
  float s = 0.f;
  for (int i = threadIdx.x; i < GROWS; i += 256) s += term[i];
  sm[threadIdx.x] = s;
  __syncthreads();
  for (int st = 128; st > 0; st >>= 1) {
    if (threadIdx.x < st) sm[threadIdx.x] += sm[threadIdx.x + st];
    __syncthreads();
  }
  if (threadIdx.x == 0) scal[0] = sm[0];
}

// ---------------- violation count ----------------
__global__ void violation_kernel(const int* __restrict__ col,
                                 const int* __restrict__ adj,
                                 int* __restrict__ cnt) {
  int idx = blockIdx.x * 256 + threadIdx.x;  // exactly NV*DEG threads
  int v = idx >> 5;
  int same = (col[adj[idx]] == col[v]) ? 1 : 0;
  unsigned long long b = __ballot(same);
  if ((threadIdx.x & 63) == 0) atomicAdd(cnt, __popcll(b));
}

// ---------------- write colors + loss ----------------
__global__ void final_kernel(const int* __restrict__ colors,
                             const float* __restrict__ scal,
                             const unsigned long long* __restrict__ used,
                             const int* __restrict__ icnt,
                             float* __restrict__ out) {
  int i = blockIdx.x * 256 + threadIdx.x;
  if (i < NV) out[i] = (float)colors[i];
  if (i == NV) {
    float logp = scal[0];
    float nused = (float)__popcll(*used);
    float ratio = (float)icnt[1] / 1048576.0f;  // exact: count / 2^20
    float cost = nused + ratio * 100.0f;
    out[NV] = cost * (logp / 32768.0f);
  }
}

// ---------------- launch ----------------
extern "C" void kernel_launch(void* const* d_in, const int* in_sizes, int n_in,
                              void* d_out, int out_size, void* d_ws, size_t ws_size,
                              hipStream_t stream) {
  const float* emb  = (const float*)d_in[0];
  const int*   adj  = (const int*)d_in[1];
  const int*   ord  = (const int*)d_in[2];
  const float* W1   = (const float*)d_in[3];
  const float* b1   = (const float*)d_in[4];
  const float* W2   = (const float*)d_in[5];
  const float* b2   = (const float*)d_in[6];
  const float* W3   = (const float*)d_in[7];
  const float* b3   = (const float*)d_in[8];
  const float* W4   = (const float*)d_in[9];
  const float* b4   = (const float*)d_in[10];
  float* out = (float*)d_out;

  const size_t MB = 1024 * 1024;
  // M-tile from ws_size (constant across calls -> graph-capture safe).
  // Per-row GEMM arithmetic independent of mt -> bit-identical logits.
  int mt;
  if (ws_size >= 175 * MB)      mt = 32768;  // full-M (needs ~174.9 MB)
  else if (ws_size >= 52 * MB)  mt = 8192;
  else                          mt = 4096;

  char* ws = (char*)d_ws;
  // small state at base (never aliases GEMM region)
  int*   col32 = (int*)  (ws);                 // 128 KB
  int*   pos   = (int*)  (ws + 131072);        // 128 KB
  float* term  = (float*)(ws + 262144);        // 128 KB
  float* scal  = (float*)(ws + 393216);
  unsigned long long* used = (unsigned long long*)(ws + 393216 + 64);
  int*   icnt  = (int*)  (ws + 393216 + 128);
  unsigned* perm = (unsigned*)(ws + 512 * 1024);  // 32768*13*4 = 1.7 MB
  float* logit = (float*)(ws + 3 * MB);           // 6.55 MB, lives whole run
  size_t h1b = (size_t)mt * EMB * 4;
  float* H1t   = (float*)(ws + 10 * MB);
  float* H2t   = (float*)(ws + 10 * MB + h1b);
  float* H3t   = (float*)(ws + 10 * MB + 2 * h1b);
  float* y     = (float*)(ws + 10 * MB);          // overlays H1t (dead after L2)

  dim3 blk(256);
  // 0) init colors/pos (pos needed by fused L4 epilogue)
  initpos_kernel<<<NV / 256, 256, 0, stream>>>(ord, col32, pos, used, icnt);

  // 1) batched MLP; L4 fuses y = logit + gumbel
  for (int t = 0; t < NV / mt; ++t) {
    const float* embT = emb + (size_t)t * mt * EMB;
    gemm128<<<dim3(EMB / 128, mt / 128), blk, 0, stream>>>(
        embT, W1, b1, H1t, mt, EMB, EMB, 1, 0);
    gemm128<<<dim3(EMB / 128, mt / 128), blk, 0, stream>>>(
        H1t, W2, b2, H2t, mt, EMB, EMB, 1, 0);
    gemm128<<<dim3((H3DIM + 127) / 128, mt / 128), blk, 0, stream>>>(
        H2t, W3, b3, H3t, mt, H3DIM, EMB, 1, 1);   // nguard: N=281
    gemm_l4<<<dim3(1, mt / TILE), blk, 0, stream>>>(
        H3t, W4, b4, logit, y, pos, t * mt, NC, H3DIM);
  }

  // 2) per-position rank lists (off the critical path)
  rank_kernel<<<(GROWS + 3) / 4, 256, 0, stream>>>(y, perm);

  // 3) true-dependency dataflow coloring (one lane per position)
  color_dataflow4<<<NV / 64, 64, 0, stream>>>(perm, adj, ord, pos, col32, used);

  // 4) parallel logp reconstruction + violations
  logp_kernel<<<8192, 256, 0, stream>>>(logit, adj, ord, pos, col32, term);
  violation_kernel<<<(NV * DEG) / 256, 256, 0, stream>>>(col32, adj, icnt + 1);
  sum_kernel<<<1, 256, 0, stream>>>(term, scal);

  // 5) outputs
  final_kernel<<<(NV + 1 + 255) / 256, 256, 0, stream>>>(col32, scal, used, icnt, out);
}

// Round 11
// 1367.028 us; speedup vs baseline: 1.0369x; 1.0369x over previous
//
#include <hip/hip_runtime.h>
#include <cstdint>
#include <cstddef>

#define NV    32768
#define EMB   512
#define DEG   32
#define NC    50
#define H3DIM 281
#define GROWS 32767            // N-1 gumbel rows
#define WGUARD (1u << 20)      // bounded spin: no infinite hang

// ---------------- threefry2x32, key = jax.random.key(42) -> (0, 42) ----------------
__device__ __forceinline__ void threefry(unsigned x0, unsigned x1,
                                         unsigned& y0, unsigned& y1) {
  const unsigned ks0 = 0u, ks1 = 42u, ks2 = 0x1BD11BDAu ^ 42u;
  x0 += ks0; x1 += ks1;
#define TFR(r) { x0 += x1; x1 = (x1 << (r)) | (x1 >> (32 - (r))); x1 ^= x0; }
  TFR(13) TFR(15) TFR(26) TFR(6)  x0 += ks1; x1 += ks2 + 1u;
  TFR(17) TFR(29) TFR(16) TFR(24) x0 += ks2; x1 += ks0 + 2u;
  TFR(13) TFR(15) TFR(26) TFR(6)  x0 += ks0; x1 += ks1 + 3u;
  TFR(17) TFR(29) TFR(16) TFR(24) x0 += ks1; x1 += ks2 + 4u;
  TFR(13) TFR(15) TFR(26) TFR(6)  x0 += ks2; x1 += ks0 + 5u;
#undef TFR
  y0 = x0; y1 = x1;
}

// partitionable threefry (jax >= 0.5 default): bits(i) = xor of threefry(key, (0, i))
__device__ __forceinline__ float gumbel_at(unsigned idx) {
  unsigned y0, y1;
  threefry(0u, idx, y0, y1);
  unsigned bits = y0 ^ y1;
  unsigned fb = (bits >> 9) | 0x3F800000u;
  float f = __uint_as_float(fb) - 1.0f;
  float u = fmaxf(f, 1.17549435e-38f);
  return -logf(-logf(u));
}

// ---------------- 128x128 fp32 GEMM, BK=32, split-block micro-tile ----------------
// Per-output arithmetic: single accumulator, k-ascending fmaf — bit-identical
// across all scheduling/mapping variants (rounds 2-10 all absmax 0.0).
// Inner-loop reads use 16B-stride split blocks (cols tx*4 and 64+tx*4):
// 2-way LDS bank aliasing only (free on wave64), vs 4-way at 32B stride.
__global__ __launch_bounds__(256) void gemm128(
    const float* __restrict__ A, const float* __restrict__ W,
    const float* __restrict__ bias, float* __restrict__ C,
    int M, int N, int K, int act, int nguard) {
  __shared__ float As[32][132];   // [k][m], padded
  __shared__ float Bs[32][128];   // [k][n] — unpadded (DMA-contiguous)
  int tid = threadIdx.x;
  int bm = blockIdx.y * 128;
  int bn = blockIdx.x * 128;
  int tx = tid & 15, ty = tid >> 4;  // 16x16 threads, 8x8 acc in 4+4 split blocks
  int wave = tid >> 6, lane = tid & 63;
  float acc[8][8];
#pragma unroll
  for (int i = 0; i < 8; ++i)
#pragma unroll
    for (int j = 0; j < 8; ++j) acc[i][j] = 0.f;

  for (int k0 = 0; k0 < K; k0 += 32) {
    // A tile: 128 rows x 32 k = 1024 float4, 4 per thread (transposed store)
#pragma unroll
    for (int l = 0; l < 4; ++l) {
      int idx = tid + l * 256;
      int row = idx >> 3, cc = (idx & 7) * 4;
      float4 av = *(const float4*)(A + (size_t)(bm + row) * K + (k0 + cc));
      As[cc + 0][row] = av.x; As[cc + 1][row] = av.y;
      As[cc + 2][row] = av.z; As[cc + 3][row] = av.w;
    }
    // B tile: 32 k-rows x 128 cols = 1024 float4
    if (!nguard) {
      // direct global->LDS DMA: dest = wave-uniform base + lane*16
#pragma unroll
      for (int l = 0; l < 4; ++l) {
        int idx = l * 256 + wave * 64 + lane;
        int row = idx >> 5, cc = (idx & 31) * 4;
        const float* gp = W + (size_t)(k0 + row) * N + (bn + cc);
        char* lp = (char*)Bs + (size_t)(l * 256 + wave * 64) * 16;
        __builtin_amdgcn_global_load_lds(
            (const __attribute__((address_space(1))) void*)gp,
            (__attribute__((address_space(3))) void*)lp, 16, 0, 0);
      }
    } else {
#pragma unroll
      for (int l = 0; l < 4; ++l) {
        int idx = tid + l * 256;
        int row = idx >> 5, cc = (idx & 31) * 4;
        int gc = bn + cc;
        const float* bp = W + (size_t)(k0 + row) * N + gc;
        float4 bv;
        bv.x = (gc + 0 < N) ? bp[0] : 0.f;
        bv.y = (gc + 1 < N) ? bp[1] : 0.f;
        bv.z = (gc + 2 < N) ? bp[2] : 0.f;
        bv.w = (gc + 3 < N) ? bp[3] : 0.f;
        *(float4*)&Bs[row][cc] = bv;
      }
    }
    __syncthreads();
#pragma unroll
    for (int kk = 0; kk < 32; ++kk) {
      // split blocks: rows {ty*4+i, 64+ty*4+i}, cols {tx*4+j, 64+tx*4+j}
      float4 a0 = *(const float4*)&As[kk][ty * 4];
      float4 a1 = *(const float4*)&As[kk][64 + ty * 4];
      float4 b0 = *(const float4*)&Bs[kk][tx * 4];
      float4 b1 = *(const float4*)&Bs[kk][64 + tx * 4];
      float a[8] = {a0.x, a0.y, a0.z, a0.w, a1.x, a1.y, a1.z, a1.w};
      float b[8] = {b0.x, b0.y, b0.z, b0.w, b1.x, b1.y, b1.z, b1.w};
#pragma unroll
      for (int i = 0; i < 8; ++i)
#pragma unroll
        for (int j = 0; j < 8; ++j)
          acc[i][j] = fmaf(a[i], b[j], acc[i][j]);
    }
    __syncthreads();
  }
#pragma unroll
  for (int i = 0; i < 8; ++i) {
    int row = bm + ((i < 4) ? (ty * 4 + i) : (64 + ty * 4 + i - 4));
#pragma unroll
    for (int j = 0; j < 8; ++j) {
      int cn = bn + ((j < 4) ? (tx * 4 + j) : (64 + tx * 4 + j - 4));
      if (cn < N) {
        float v = acc[i][j] + bias[cn];
        if (act) v = (v >= 0.f) ? v : 0.01f * v;
        C[(size_t)row * N + cn] = v;
      }
    }
  }
}

// ---------------- L4 GEMM (K=281, N=50) with fused y = logit + gumbel epilogue ----------------
#define TILE 64
#define BK   16
__global__ __launch_bounds__(256) void gemm_l4(
    const float* __restrict__ A, const float* __restrict__ W,
    const float* __restrict__ bias, float* __restrict__ Clog,
    float* __restrict__ y, const int* __restrict__ pos,
    int row0, int N, int K) {
  __shared__ float As[BK][TILE + 1];
  __shared__ float Bs[BK][TILE];
  int tid = threadIdx.x;
  int bm = blockIdx.y * TILE;
  int tx = tid & 15, ty = tid >> 4;
  int ar = tid >> 2;
  int ac = (tid & 3) * 4;
  int br = tid >> 4;
  int bc = (tid & 15) * 4;
  float acc[4][4] = {{0.f,0.f,0.f,0.f},{0.f,0.f,0.f,0.f},{0.f,0.f,0.f,0.f},{0.f,0.f,0.f,0.f}};

  for (int k0 = 0; k0 < K; k0 += BK) {
    {
      int gk = k0 + ac;
      const float* ap = A + (size_t)(bm + ar) * K + gk;
      As[ac + 0][ar] = (gk + 0 < K) ? ap[0] : 0.f;
      As[ac + 1][ar] = (gk + 1 < K) ? ap[1] : 0.f;
      As[ac + 2][ar] = (gk + 2 < K) ? ap[2] : 0.f;
      As[ac + 3][ar] = (gk + 3 < K) ? ap[3] : 0.f;
    }
    {
      int gr = k0 + br;
      const float* bp = W + (size_t)gr * N + bc;
      bool rok = gr < K;
      Bs[br][bc + 0] = (rok && bc + 0 < N) ? bp[0] : 0.f;
      Bs[br][bc + 1] = (rok && bc + 1 < N) ? bp[1] : 0.f;
      Bs[br][bc + 2] = (rok && bc + 2 < N) ? bp[2] : 0.f;
      Bs[br][bc + 3] = (rok && bc + 3 < N) ? bp[3] : 0.f;
    }
    __syncthreads();
#pragma unroll
    for (int kk = 0; kk < BK; ++kk) {
      float a[4], b[4];
#pragma unroll
      for (int i = 0; i < 4; ++i) a[i] = As[kk][ty * 4 + i];
#pragma unroll
      for (int j = 0; j < 4; ++j) b[j] = Bs[kk][tx * 4 + j];
#pragma unroll
      for (int i = 0; i < 4; ++i)
#pragma unroll
        for (int j = 0; j < 4; ++j)
          acc[i][j] = fmaf(a[i], b[j], acc[i][j]);
    }
    __syncthreads();
  }
#pragma unroll
  for (int i = 0; i < 4; ++i) {
    int v = row0 + bm + ty * 4 + i;   // global vertex id
    int p = pos[v];
#pragma unroll
    for (int j = 0; j < 4; ++j) {
      int cn = tx * 4 + j;
      if (cn < N) {
        float val = acc[i][j] + bias[cn];
        Clog[(size_t)v * N + cn] = val;
        if (p > 0)   // y row p; same add order as reference (logit + gumbel)
          y[(size_t)p * N + cn] = val + gumbel_at((unsigned)((p - 1) * N + cn));
      }
    }
  }
}

// ---------------- init: colors/pos/counters in one pass ----------------
__global__ void initpos_kernel(const int* __restrict__ order,
                               int* __restrict__ colors, int* __restrict__ pos,
                               unsigned long long* __restrict__ used,
                               int* __restrict__ icnt) {
  int i = blockIdx.x * 256 + threadIdx.x;
  if (i < NV) { colors[i] = -1; pos[order[i]] = i; }
  if (i == 0) { *used = 0ull; icnt[0] = 0; icnt[1] = 0; }
}

// ---------------- per-position descending-sort permutation of y (50 values) ----------------
// rank[c] = #{c' : y[c'] > y[c]  or  (y[c']==y[c] and c'<c)}  -> stable descending order.
// First unmasked color in this order == argmax of masked y (jnp.argmax tie-break).
__global__ __launch_bounds__(256) void rank_kernel(const float* __restrict__ y,
                                                   unsigned* __restrict__ perm) {
  __shared__ unsigned char sh[4][64];
  int w = threadIdx.x >> 6, lane = threadIdx.x & 63;
  int p = blockIdx.x * 4 + w + 1;
  bool active = (p < NV);
  float val = (active && lane < NC) ? y[(size_t)p * NC + lane] : 0.f;
  int rank = 0;
#pragma unroll
  for (int c = 0; c < NC; ++c) {
    float o = __shfl(val, c);
    rank += (o > val) || (o == val && c < lane);
  }
  if (active && lane < NC) sh[w][rank] = (unsigned char)lane;
  __syncthreads();
  if (active && lane < 13) perm[(size_t)p * 13 + lane] = ((unsigned*)sh[w])[lane];
}

// ---------------- true-dependency dataflow coloring, register-rank fire ----------------
// One lane per position; spins (RELAXED agent-scope, s_sleep(2) backoff — the
// proven-best 323us config) on its earlier-neighbor colors.
__global__ __launch_bounds__(64) void color_dataflow4(
    const unsigned* __restrict__ perm, const int* __restrict__ adj,
    const int* __restrict__ order, const int* __restrict__ pos,
    int* colors, unsigned long long* used) {
  int lane = threadIdx.x;
  int p = blockIdx.x * 64 + lane;     // position owned by this lane
  int v = order[p];
  int u[DEG];
  const int* arow = adj + (size_t)v * DEG;
#pragma unroll
  for (int j = 0; j < DEG; ++j) u[j] = arow[j];
  unsigned pend = 0;
#pragma unroll
  for (int j = 0; j < DEG; ++j)
    if (pos[u[j]] < p) pend |= 1u << j;
  unsigned pm[13];
#pragma unroll
  for (int i = 0; i < 13; ++i) pm[i] = perm[(size_t)p * 13 + i];  // row 0 garbage, unused

  unsigned long long colmask = 0ull;
  unsigned long long um = 0ull;
  bool done = false;
  if (p == 0) {
    __hip_atomic_store(colors + v, 0, __ATOMIC_RELAXED, __HIP_MEMORY_SCOPE_AGENT);
    um = 1ull; done = true; pend = 0;
  }
  unsigned guard = 0;
  while (true) {
    unsigned newpend = pend;
#pragma unroll
    for (int j = 0; j < DEG; ++j) {
      if (pend & (1u << j)) {
        int c = __hip_atomic_load(colors + u[j], __ATOMIC_RELAXED, __HIP_MEMORY_SCOPE_AGENT);
        if (c >= 0) { colmask |= 1ull << c; newpend &= ~(1u << j); }
      }
    }
    pend = newpend;
    if (++guard > WGUARD) pend = 0;  // halt guarantee: fire with partial mask
    if (!done && pend == 0) {
      int bc = -1;
#pragma unroll
      for (int r = 0; r < NC; ++r) {   // constant indices -> stays in registers
        int c = (int)((pm[r >> 2] >> ((r & 3) * 8)) & 0xffu);
        if (bc < 0 && !((colmask >> c) & 1ull)) bc = c;
      }
      __hip_atomic_store(colors + v, bc, __ATOMIC_RELAXED, __HIP_MEMORY_SCOPE_AGENT);
      um |= 1ull << bc;
      done = true;
    }
    if (__ballot(pend != 0) == 0ull) break;  // every lane in wave has fired
    __builtin_amdgcn_s_sleep(2);
  }
#pragma unroll
  for (int off = 1; off < 64; off <<= 1) um |= __shfl_xor(um, off);
  if (lane == 0) atomicOr(used, um);
}

// ---------------- parallel logp reconstruction (one wave per position) ----------------
__global__ __launch_bounds__(256) void logp_kernel(
    const float* __restrict__ logit, const int* __restrict__ adj,
    const int* __restrict__ order, const int* __restrict__ pos,
    const int* __restrict__ colors, float* __restrict__ term) {
  int wid = blockIdx.x * 4 + (threadIdx.x >> 6);
  int lane = threadIdx.x & 63;
  int p = wid + 1;
  if (p >= NV) return;
  int v = order[p];
  int cchosen = colors[v];
  unsigned long long bits = 0ull;
  if (lane < DEG) {
    int u = adj[v * DEG + lane];
    if (pos[u] < p) bits = 1ull << colors[u];  // color at time p == final color
  }
#pragma unroll
  for (int off = 1; off < 64; off <<= 1) bits |= __shfl_xor(bits, off);
  bool masked = (bits >> lane) & 1ull;
  float xv = (lane < NC) ? logit[v * NC + lane] : -INFINITY;
  float x = (lane < NC && !masked) ? xv : -INFINITY;
  float xm = x;
#pragma unroll
  for (int off = 1; off < 64; off <<= 1) xm = fmaxf(xm, __shfl_xor(xm, off));
  float ex = expf(x - xm);
  float S = ex;
#pragma unroll
  for (int off = 1; off < 64; off <<= 1) S += __shfl_xor(S, off);
  float ec = __shfl(ex, cchosen);
  float pr = ec / S;
  if (lane == 0) term[p - 1] = logf(pr + 1e-8f) - logf(1e-8f);
}

// ---------------- deterministic sum of 32767 terms ----------------
__global__ __launch_bounds__(256) void sum_kernel(const float* __restrict__ term,
                                                  float* __restrict__ scal) {
  __shared__ float sm[256];
  float s = 0.f;
  for (int i = threadIdx.x; i < GROWS; i += 256) s += term[i];
  sm[threadIdx.x] = s;
  __syncthreads();
  for (int st = 128; st > 0; st >>= 1) {
    if (threadIdx.x < st) sm[threadIdx.x] += sm[threadIdx.x + st];
    __syncthreads();
  }
  if (threadIdx.x == 0) scal[0] = sm[0];
}

// ---------------- violation count ----------------
__global__ void violation_kernel(const int* __restrict__ col,
                                 const int* __restrict__ adj,
                                 int* __restrict__ cnt) {
  int idx = blockIdx.x * 256 + threadIdx.x;  // exactly NV*DEG threads
  int v = idx >> 5;
  int same = (col[adj[idx]] == col[v]) ? 1 : 0;
  unsigned long long b = __ballot(same);
  if ((threadIdx.x & 63) == 0) atomicAdd(cnt, __popcll(b));
}

// ---------------- write colors + loss ----------------
__global__ void final_kernel(const int* __restrict__ colors,
                             const float* __restrict__ scal,
                             const unsigned long long* __restrict__ used,
                             const int* __restrict__ icnt,
                             float* __restrict__ out) {
  int i = blockIdx.x * 256 + threadIdx.x;
  if (i < NV) out[i] = (float)colors[i];
  if (i == NV) {
    float logp = scal[0];
    float nused = (float)__popcll(*used);
    float ratio = (float)icnt[1] / 1048576.0f;  // exact: count / 2^20
    float cost = nused + ratio * 100.0f;
    out[NV] = cost * (logp / 32768.0f);
  }
}

// ---------------- launch ----------------
extern "C" void kernel_launch(void* const* d_in, const int* in_sizes, int n_in,
                              void* d_out, int out_size, void* d_ws, size_t ws_size,
                              hipStream_t stream) {
  const float* emb  = (const float*)d_in[0];
  const int*   adj  = (const int*)d_in[1];
  const int*   ord  = (const int*)d_in[2];
  const float* W1   = (const float*)d_in[3];
  const float* b1   = (const float*)d_in[4];
  const float* W2   = (const float*)d_in[5];
  const float* b2   = (const float*)d_in[6];
  const float* W3   = (const float*)d_in[7];
  const float* b3   = (const float*)d_in[8];
  const float* W4   = (const float*)d_in[9];
  const float* b4   = (const float*)d_in[10];
  float* out = (float*)d_out;

  const size_t MB = 1024 * 1024;
  // M-tile from ws_size (constant across calls -> graph-capture safe).
  // Per-row GEMM arithmetic independent of mt -> bit-identical logits.
  int mt;
  if (ws_size >= 175 * MB)      mt = 32768;  // full-M (needs ~174.9 MB)
  else if (ws_size >= 52 * MB)  mt = 8192;
  else                          mt = 4096;

  char* ws = (char*)d_ws;
  // small state at base (never aliases GEMM region)
  int*   col32 = (int*)  (ws);                 // 128 KB
  int*   pos   = (int*)  (ws + 131072);        // 128 KB
  float* term  = (float*)(ws + 262144);        // 128 KB
  float* scal  = (float*)(ws + 393216);
  unsigned long long* used = (unsigned long long*)(ws + 393216 + 64);
  int*   icnt  = (int*)  (ws + 393216 + 128);
  unsigned* perm = (unsigned*)(ws + 512 * 1024);  // 32768*13*4 = 1.7 MB
  float* logit = (float*)(ws + 3 * MB);           // 6.55 MB, lives whole run
  size_t h1b = (size_t)mt * EMB * 4;
  float* H1t   = (float*)(ws + 10 * MB);
  float* H2t   = (float*)(ws + 10 * MB + h1b);
  float* H3t   = (float*)(ws + 10 * MB + 2 * h1b);
  float* y     = (float*)(ws + 10 * MB);          // overlays H1t (dead after L2)

  dim3 blk(256);
  // 0) init colors/pos (pos needed by fused L4 epilogue)
  initpos_kernel<<<NV / 256, 256, 0, stream>>>(ord, col32, pos, used, icnt);

  // 1) batched MLP; L4 fuses y = logit + gumbel
  for (int t = 0; t < NV / mt; ++t) {
    const float* embT = emb + (size_t)t * mt * EMB;
    gemm128<<<dim3(EMB / 128, mt / 128), blk, 0, stream>>>(
        embT, W1, b1, H1t, mt, EMB, EMB, 1, 0);
    gemm128<<<dim3(EMB / 128, mt / 128), blk, 0, stream>>>(
        H1t, W2, b2, H2t, mt, EMB, EMB, 1, 0);
    gemm128<<<dim3((H3DIM + 127) / 128, mt / 128), blk, 0, stream>>>(
        H2t, W3, b3, H3t, mt, H3DIM, EMB, 1, 1);   // nguard: N=281
    gemm_l4<<<dim3(1, mt / TILE), blk, 0, stream>>>(
        H3t, W4, b4, logit, y, pos, t * mt, NC, H3DIM);
  }

  // 2) per-position rank lists (off the critical path)
  rank_kernel<<<(GROWS + 3) / 4, 256, 0, stream>>>(y, perm);

  // 3) true-dependency dataflow coloring (one lane per position)
  color_dataflow4<<<NV / 64, 64, 0, stream>>>(perm, adj, ord, pos, col32, used);

  // 4) parallel logp reconstruction + violations
  logp_kernel<<<8192, 256, 0, stream>>>(logit, adj, ord, pos, col32, term);
  violation_kernel<<<(NV * DEG) / 256, 256, 0, stream>>>(col32, adj, icnt + 1);
  sum_kernel<<<1, 256, 0, stream>>>(term, scal);

  // 5) outputs
  final_kernel<<<(NV + 1 + 255) / 256, 256, 0, stream>>>(col32, scal, used, icnt, out);
}